// Round 8
// baseline (356.783 us; speedup 1.0000x reference)
//
#include <hip/hip_runtime.h>
#include <math.h>

// Round 8: round 7's pipeline (4-step unroll, one barrier/4 steps, zr prefetch
// one sub-step ahead on wave0, pv double-buffer on wave1) but with the round-4
// style shuffle gather: p0..p3 = shfl(partial, 4o+j) delivers the linear sum
// directly to lane o, so decoder state AND global stores live on contiguous
// lanes 0..9. Round 7's stride-4 store lanes tripled WRITE_SIZE (partial-sector
// writes + RMW allocate fetches) -- consecutive store lanes fix that.
// All FP chains byte-identical order -> numerics unchanged. T % 4 == 0.

typedef float v2f __attribute__((ext_vector_type(2)));

__global__ __launch_bounds__(128, 4) void snn_step_kernel(
    const float* __restrict__ x,       // [B,1,15,15]
    const float* __restrict__ conv_w,  // [2,1,4,4]
    const float* __restrict__ conv_b,  // [2]
    const float* __restrict__ lin_w,   // [10,72]
    const float* __restrict__ lin_b,   // [10]
    float* __restrict__ out,           // spk_out[B,10] ++ mem_rec[T,B,10] ++ spk_rec[T,B,10]
    int T, int B)
{
    const int b   = blockIdx.x;
    const int tid = threadIdx.x;
    const int w   = tid & 63;   // lane within wave
    const int wv  = tid >> 6;   // 0 = enc+conv wave, 1 = lin+dec wave

    __shared__ float s_convw[32];
    __shared__ float s_convb[2];
    __shared__ float s_linw[720];
    __shared__ float s_linb[10];
    __shared__ float s_z[2][304];   // wave0-private, double-buffered swizzled 15x15 (+pad)
    __shared__ float s_p[8][72];    // wave0 -> wave1 handoff, 8-deep

    // ---- cooperative weight staging (128 threads) ----
    if (tid < 32) s_convw[tid] = conv_w[tid];
    if (tid < 2)  s_convb[tid] = conv_b[tid];
    for (int j = tid; j < 720; j += 128) s_linw[j] = lin_w[j];
    if (tid < 10) s_linb[tid] = lin_b[tid];
    __syncthreads();

    // ===== wave0 state =====
    float ve[4], cur[4];
    int   zoff[4];
    v2f   wreg2[16];
    v2f   cb2 = (v2f){0.0f, 0.0f};
    int   wbase = 0;
    bool  convlane = false;
    float zrbuf[2][25];             // double-buffered conv window registers

    // ===== wave1 state =====
    // lane w computes the partial for output lo = w>>2, quarter lq = w&3;
    // decoder state + stores live on contiguous lanes 0..9.
    float lwreg[18];
    float lbias = 0.0f;
    float v = 0.0f, i_syn = 0.0f, sc = 0.0f;
    float svv[4], svs[4];           // deferred store values per sub-step
    const int lo = w >> 2, lq = w & 3;
    const bool olane = (w < 10);
    const size_t BO = (size_t)B * 10;
    float* mp  = out + BO + (size_t)b * 10 + w;          // lanes 0..9 contiguous
    float* spp = mp + (size_t)T * BO;

    const int roff[5] = {0, 16, 35, 51, 70};

    if (wv == 0) {
        // encoder: lane w owns pixels w, w+64, w+128, w+192 (branchless; p>=225 -> pad)
#pragma unroll
        for (int k = 0; k < 4; ++k) {
            int p = w + 64 * k;
            bool act = (p < 225);
            ve[k]  = 0.0f;
            cur[k] = act ? __fmul_rn(x[(size_t)b * 225 + p], 10.0f) : 0.0f;
            int row = p / 15, col = p - row * 15;
            zoff[k] = row * 16 + col + 3 * (row >> 1);   // swizzle; rows>=15 land in pad
        }
        convlane = (w < 36);
        int py = w / 6, px = w - py * 6;
        int wb = 35 * py + 2 * px;
        wbase = wb < 229 ? wb : 229;   // clamp keeps dead lanes in-bounds
#pragma unroll
        for (int kk = 0; kk < 16; ++kk) wreg2[kk] = (v2f){s_convw[kk], s_convw[16 + kk]};
        cb2 = (v2f){s_convb[0], s_convb[1]};

        // prologue: enc(0) -> s_z[0], then prefetch zr(0) into zrbuf[0]
#pragma unroll
        for (int k = 0; k < 4; ++k) {
            float vn = __fadd_rn(ve[k], __fmul_rn(0.1f, __fsub_rn(cur[k], ve[k])));
            bool  sp = (vn > 1.0f);
            ve[k] = sp ? 0.0f : vn;
            s_z[0][zoff[k]] = sp ? 1.0f : 0.0f;
        }
        const float* zc = &s_z[0][wbase];
#pragma unroll
        for (int r = 0; r < 5; ++r)
#pragma unroll
            for (int cc = 0; cc < 5; ++cc)
                zrbuf[0][r * 5 + cc] = zc[roff[r] + cc];
    } else {
#pragma unroll
        for (int j = 0; j < 18; ++j) {
            int idx = lo * 72 + lq * 18 + j;
            lwreg[j] = s_linw[idx < 720 ? idx : 719];   // clamp for lanes >= 40
        }
        lbias = olane ? s_linb[w] : 0.0f;
    }

    auto issue_stores = [&]() {
        if (olane) {
#pragma unroll
            for (int k = 0; k < 4; ++k) {
                mp[(size_t)k * BO]  = svv[k];
                spp[(size_t)k * BO] = svs[k];
            }
        }
        mp  += 4 * BO;
        spp += 4 * BO;
    };

    // wave1: linear+decoder for one step; pv already in registers.
    // Gather via 4x shfl to lane lo==w (round-4 scheme): store lanes stay 0..9.
    auto lin_comp = [&](const float* pv, int k) {
        float partial = 0.0f;
#pragma unroll
        for (int j = 0; j < 18; ++j)
            partial = fmaf(lwreg[j], pv[j], partial);
        const int base = 4 * (w & 15);
        float p0 = __shfl(partial, base + 0);
        float p1 = __shfl(partial, base + 1);
        float p2 = __shfl(partial, base + 2);
        float p3 = __shfl(partial, base + 3);
        float lin = __fadd_rn(__fadd_rn(__fadd_rn(__fadd_rn(p0, p1), p2), p3), lbias);

        float vd  = __fadd_rn(v, __fmul_rn(0.1f, __fsub_rn(i_syn, v)));
        float id  = __fsub_rn(i_syn, __fmul_rn(0.2f, i_syn));
        float spk = (vd > 1.0f) ? 1.0f : 0.0f;
        v = (vd > 1.0f) ? 0.0f : vd;
        sc += spk;
        svv[k] = v;
        svs[k] = spk;
        i_syn = __fadd_rn(id, lin);
    };

    const int TI = T >> 2;   // T % 4 == 0

    for (int i = 0; i < TI; ++i) {
        if (wv == 0) {
#pragma unroll
            for (int k = 0; k < 4; ++k) {
                // encoder for step 4i+k+1 -> s_z[(k+1)&1]
#pragma unroll
                for (int kk = 0; kk < 4; ++kk) {
                    float vn = __fadd_rn(ve[kk], __fmul_rn(0.1f, __fsub_rn(cur[kk], ve[kk])));
                    bool  sp = (vn > 1.0f);
                    ve[kk] = sp ? 0.0f : vn;
                    s_z[(k + 1) & 1][zoff[kk]] = sp ? 1.0f : 0.0f;
                }
                // prefetch zr(4i+k+1) (reads queue behind the enc writes: in-order DS)
                {
                    const float* zc = &s_z[(k + 1) & 1][wbase];
#pragma unroll
                    for (int r = 0; r < 5; ++r)
#pragma unroll
                        for (int cc = 0; cc < 5; ++cc)
                            zrbuf[(k + 1) & 1][r * 5 + cc] = zc[roff[r] + cc];
                }
                // conv 4x4 (channels packed) + maxpool 2x2 for step 4i+k,
                // using zrbuf[k&1] loaded one sub-step ago (latency hidden)
                if (convlane) {
                    const float* zr = zrbuf[k & 1];
                    v2f m2 = (v2f){-INFINITY, -INFINITY};
#pragma unroll
                    for (int dy = 0; dy < 2; ++dy)
#pragma unroll
                        for (int dx = 0; dx < 2; ++dx) {
                            v2f acc = (v2f){0.0f, 0.0f};
#pragma unroll
                            for (int ky = 0; ky < 4; ++ky)
#pragma unroll
                                for (int kx = 0; kx < 4; ++kx) {
                                    float z = zr[(dy + ky) * 5 + (dx + kx)];
                                    acc = __builtin_elementwise_fma(wreg2[ky * 4 + kx],
                                                                    (v2f){z, z}, acc);
                                }
                            v2f val = acc + cb2;
                            m2 = __builtin_elementwise_max(m2, val);
                        }
                    float* pbuf = s_p[((i & 1) << 2) | k];
                    pbuf[w]      = m2.x;
                    pbuf[36 + w] = m2.y;
                }
            }
        } else {
            if (i >= 2) issue_stores();            // steps 4(i-2)..4(i-2)+3
            if (i >= 1) {
                const int sbase = ((i - 1) & 1) << 2;
                float pvbuf[2][18];
                // prefetch k=0
                {
                    const float* pp = &s_p[sbase][lq * 18];
#pragma unroll
                    for (int j = 0; j < 18; ++j) pvbuf[0][j] = pp[j];
                }
#pragma unroll
                for (int k = 0; k < 4; ++k) {
                    if (k < 3) {                    // prefetch k+1 before k's fma chain
                        const float* pp = &s_p[sbase | (k + 1)][lq * 18];
#pragma unroll
                        for (int j = 0; j < 18; ++j) pvbuf[(k + 1) & 1][j] = pp[j];
                    }
                    lin_comp(pvbuf[k & 1], k);      // steps 4(i-1)..4(i-1)+3
                }
            }
        }
        __syncthreads();
    }

    // ---- epilogue (wave1): pending stores T-8..T-5, compute+store T-4..T-1 ----
    if (wv == 1) {
        issue_stores();                             // steps T-8..T-5
        const int sbase = ((TI - 1) & 1) << 2;
#pragma unroll
        for (int k = 0; k < 4; ++k) {
            float pv[18];
            const float* pp = &s_p[sbase | k][lq * 18];
#pragma unroll
            for (int j = 0; j < 18; ++j) pv[j] = pp[j];
            lin_comp(pv, k);                        // steps T-4..T-1
        }
        issue_stores();
        if (olane) out[(size_t)b * 10 + w] = sc;
    }
}

extern "C" void kernel_launch(void* const* d_in, const int* in_sizes, int n_in,
                              void* d_out, int out_size, void* d_ws, size_t ws_size,
                              hipStream_t stream) {
    const float* x      = (const float*)d_in[0];
    const float* conv_w = (const float*)d_in[1];
    const float* conv_b = (const float*)d_in[2];
    const float* lin_w  = (const float*)d_in[3];
    const float* lin_b  = (const float*)d_in[4];
    float* out = (float*)d_out;

    const int B = in_sizes[0] / 225;             // x is [B,1,15,15]
    const int T = (out_size / (B * 10) - 1) / 2; // out = B*10 * (1 + 2T); T=300 (div by 4)

    snn_step_kernel<<<B, 128, 0, stream>>>(x, conv_w, conv_b, lin_w, lin_b, out, T, B);
}

// Round 9
// 265.204 us; speedup vs baseline: 1.3453x; 1.3453x over previous
//
#include <hip/hip_runtime.h>
#include <math.h>

// Round 9: round 6 structure verbatim (best so far: 4-step unrolled
// producer/consumer, one barrier per 4 steps, stores deferred one iteration),
// with ONE change: wave1's s_part LDS round-trip is replaced by the 4x __shfl
// gather (partial sums delivered straight to lane lo; stores stay on
// contiguous lanes 0..9).
// Rounds 7/8 regressed because persistent pointer-indexed local arrays
// (zrbuf/pvbuf) were demoted to scratch -> 243..699 MB of HBM write traffic.
// This version keeps all local arrays short-lived and same-scope (SROA-safe).
// All FP chains byte-identical order -> numerics unchanged. T % 4 == 0.

typedef float v2f __attribute__((ext_vector_type(2)));

__global__ __launch_bounds__(128, 4) void snn_step_kernel(
    const float* __restrict__ x,       // [B,1,15,15]
    const float* __restrict__ conv_w,  // [2,1,4,4]
    const float* __restrict__ conv_b,  // [2]
    const float* __restrict__ lin_w,   // [10,72]
    const float* __restrict__ lin_b,   // [10]
    float* __restrict__ out,           // spk_out[B,10] ++ mem_rec[T,B,10] ++ spk_rec[T,B,10]
    int T, int B)
{
    const int b   = blockIdx.x;
    const int tid = threadIdx.x;
    const int w   = tid & 63;   // lane within wave
    const int wv  = tid >> 6;   // 0 = enc+conv wave, 1 = lin+dec wave

    __shared__ float s_convw[32];
    __shared__ float s_convb[2];
    __shared__ float s_linw[720];
    __shared__ float s_linb[10];
    __shared__ float s_z[2][304];   // wave0-private, double-buffered swizzled 15x15 (+pad)
    __shared__ float s_p[8][72];    // wave0 -> wave1 handoff, 8-deep

    // ---- cooperative weight staging (128 threads) ----
    if (tid < 32) s_convw[tid] = conv_w[tid];
    if (tid < 2)  s_convb[tid] = conv_b[tid];
    for (int j = tid; j < 720; j += 128) s_linw[j] = lin_w[j];
    if (tid < 10) s_linb[tid] = lin_b[tid];
    __syncthreads();

    // ===== wave0 state =====
    float ve[4], cur[4];
    int   zoff[4];
    v2f   wreg2[16];
    v2f   cb2 = (v2f){0.0f, 0.0f};
    int   wbase = 0;
    bool  convlane = false;

    // ===== wave1 state =====
    // lane w computes the partial for output lo = w>>2, quarter lq = w&3;
    // gathered sum + decoder state + stores live on contiguous lanes 0..9.
    float lwreg[18];
    float lbias = 0.0f;
    float v = 0.0f, i_syn = 0.0f, sc = 0.0f;
    float svv[4], svs[4];           // deferred store values per sub-step
    const int lo = w >> 2, lq = w & 3;
    const bool olane = (w < 10);
    const size_t BO = (size_t)B * 10;
    float* mp  = out + BO + (size_t)b * 10 + w;          // lanes 0..9 contiguous
    float* spp = mp + (size_t)T * BO;

    const int roff[5] = {0, 16, 35, 51, 70};

    if (wv == 0) {
        // encoder: lane w owns pixels w, w+64, w+128, w+192 (branchless; p>=225 -> pad)
#pragma unroll
        for (int k = 0; k < 4; ++k) {
            int p = w + 64 * k;
            bool act = (p < 225);
            ve[k]  = 0.0f;
            cur[k] = act ? __fmul_rn(x[(size_t)b * 225 + p], 10.0f) : 0.0f;
            int row = p / 15, col = p - row * 15;
            zoff[k] = row * 16 + col + 3 * (row >> 1);   // swizzle; rows>=15 land in pad
        }
        convlane = (w < 36);
        int py = w / 6, px = w - py * 6;
        int wb = 35 * py + 2 * px;
        wbase = wb < 229 ? wb : 229;   // clamp keeps dead lanes in-bounds
#pragma unroll
        for (int kk = 0; kk < 16; ++kk) wreg2[kk] = (v2f){s_convw[kk], s_convw[16 + kk]};
        cb2 = (v2f){s_convb[0], s_convb[1]};

        // prologue: enc(0) -> s_z[0]
#pragma unroll
        for (int k = 0; k < 4; ++k) {
            float vn = __fadd_rn(ve[k], __fmul_rn(0.1f, __fsub_rn(cur[k], ve[k])));
            bool  sp = (vn > 1.0f);
            ve[k] = sp ? 0.0f : vn;
            s_z[0][zoff[k]] = sp ? 1.0f : 0.0f;
        }
    } else {
#pragma unroll
        for (int j = 0; j < 18; ++j) {
            int idx = lo * 72 + lq * 18 + j;
            lwreg[j] = s_linw[idx < 720 ? idx : 719];   // clamp for lanes >= 40
        }
        lbias = olane ? s_linb[w] : 0.0f;
    }

    // wave1: linear+decoder compute for one step; stores deferred into svv/svs[k].
    // Gather via 4x shfl: lane w receives partials of lanes 4w..4w+3 (w<10).
    auto lin_comp = [&](const float* pbuf, int k) {
        const float* pp = &pbuf[lq * 18];
        float pv[18];
#pragma unroll
        for (int j = 0; j < 18; ++j) pv[j] = pp[j];
        float partial = 0.0f;
#pragma unroll
        for (int j = 0; j < 18; ++j)
            partial = fmaf(lwreg[j], pv[j], partial);

        const int base = 4 * (w & 15);
        float p0 = __shfl(partial, base + 0);
        float p1 = __shfl(partial, base + 1);
        float p2 = __shfl(partial, base + 2);
        float p3 = __shfl(partial, base + 3);
        float lin = __fadd_rn(__fadd_rn(__fadd_rn(__fadd_rn(p0, p1), p2), p3), lbias);

        float vd  = __fadd_rn(v, __fmul_rn(0.1f, __fsub_rn(i_syn, v)));
        float id  = __fsub_rn(i_syn, __fmul_rn(0.2f, i_syn));
        float spk = (vd > 1.0f) ? 1.0f : 0.0f;
        v = (vd > 1.0f) ? 0.0f : vd;
        sc += spk;
        svv[k] = v;
        svs[k] = spk;
        i_syn = __fadd_rn(id, lin);
    };

    auto issue_stores = [&]() {
        if (olane) {
#pragma unroll
            for (int k = 0; k < 4; ++k) {
                mp[(size_t)k * BO]  = svv[k];
                spp[(size_t)k * BO] = svs[k];
            }
        }
        mp  += 4 * BO;
        spp += 4 * BO;
    };

    const int TI = T >> 2;   // T % 4 == 0

    for (int i = 0; i < TI; ++i) {
        if (wv == 0) {
#pragma unroll
            for (int k = 0; k < 4; ++k) {
                // conv window reads for step s=4i+k from s_z[k&1]
                float zr[25];
                const float* zc = &s_z[k & 1][wbase];
#pragma unroll
                for (int r = 0; r < 5; ++r)
#pragma unroll
                    for (int cc = 0; cc < 5; ++cc)
                        zr[r * 5 + cc] = zc[roff[r] + cc];

                // encoder for step s+1 -> s_z[(k+1)&1] (hides read latency)
#pragma unroll
                for (int kk = 0; kk < 4; ++kk) {
                    float vn = __fadd_rn(ve[kk], __fmul_rn(0.1f, __fsub_rn(cur[kk], ve[kk])));
                    bool  sp = (vn > 1.0f);
                    ve[kk] = sp ? 0.0f : vn;
                    s_z[(k + 1) & 1][zoff[kk]] = sp ? 1.0f : 0.0f;
                }

                // conv 4x4 (channels packed) + maxpool 2x2 -> s_p[(4i+k)&7]
                if (convlane) {
                    v2f m2 = (v2f){-INFINITY, -INFINITY};
#pragma unroll
                    for (int dy = 0; dy < 2; ++dy)
#pragma unroll
                        for (int dx = 0; dx < 2; ++dx) {
                            v2f acc = (v2f){0.0f, 0.0f};
#pragma unroll
                            for (int ky = 0; ky < 4; ++ky)
#pragma unroll
                                for (int kx = 0; kx < 4; ++kx) {
                                    float z = zr[(dy + ky) * 5 + (dx + kx)];
                                    acc = __builtin_elementwise_fma(wreg2[ky * 4 + kx],
                                                                    (v2f){z, z}, acc);
                                }
                            v2f val = acc + cb2;
                            m2 = __builtin_elementwise_max(m2, val);
                        }
                    float* pbuf = s_p[((i & 1) << 2) | k];
                    pbuf[w]      = m2.x;
                    pbuf[36 + w] = m2.y;
                }
            }
        } else {
            if (i >= 2) issue_stores();        // steps 4(i-2)..4(i-2)+3
            if (i >= 1) {
#pragma unroll
                for (int k = 0; k < 4; ++k)    // steps 4(i-1)..4(i-1)+3
                    lin_comp(s_p[(((i - 1) & 1) << 2) | k], k);
            }
        }
        __syncthreads();
    }

    // ---- epilogue (wave1): pending stores T-8..T-5, compute+store T-4..T-1 ----
    if (wv == 1) {
        issue_stores();                         // steps T-8..T-5
#pragma unroll
        for (int k = 0; k < 4; ++k)             // steps T-4..T-1
            lin_comp(s_p[(((TI - 1) & 1) << 2) | k], k);
        issue_stores();
        if (olane) out[(size_t)b * 10 + w] = sc;
    }
}

extern "C" void kernel_launch(void* const* d_in, const int* in_sizes, int n_in,
                              void* d_out, int out_size, void* d_ws, size_t ws_size,
                              hipStream_t stream) {
    const float* x      = (const float*)d_in[0];
    const float* conv_w = (const float*)d_in[1];
    const float* conv_b = (const float*)d_in[2];
    const float* lin_w  = (const float*)d_in[3];
    const float* lin_b  = (const float*)d_in[4];
    float* out = (float*)d_out;

    const int B = in_sizes[0] / 225;             // x is [B,1,15,15]
    const int T = (out_size / (B * 10) - 1) / 2; // out = B*10 * (1 + 2T); T=300 (div by 4)

    snn_step_kernel<<<B, 128, 0, stream>>>(x, conv_w, conv_b, lin_w, lin_b, out, T, B);
}

// Round 10
// 255.351 us; speedup vs baseline: 1.3972x; 1.0386x over previous
//
#include <hip/hip_runtime.h>
#include <math.h>

// Round 10: round 6 skeleton (4-step unroll, one barrier per 4 steps, s_part
// reduce, stores deferred one iteration) with the ENCODER MIGRATED to wave1,
// running ONE ITERATION AHEAD:
//   wave0 (tid 0..63):   conv4x4/maxpool only, steps 4i..4i+3,
//                        reading s_z slots (i&1)*4+k (written last iter).
//   wave1 (tid 64..127): lin+dec for steps 4i-4..4i-1 (one iter behind),
//                        encoder for steps 4i+4..4i+7 -> s_z slots ((i&1)^1)*4+k,
//                        global stores deferred one further iteration.
// Balance: ~400 vs ~350 instr/iter (was 600/240) -> less barrier idle.
// s_z 8-deep: reader/writer slot sets disjoint each iteration, one barrier
// apart. Encoder per-pixel FP sequence, conv, linear, decoder chains all
// byte-identical to round 6 -> numerics unchanged (absmax 1.0).
// No pointer-indexed persistent local arrays (scratch-demotion trap, r7/r8).
// Requires T % 4 == 0 (T=300).

typedef float v2f __attribute__((ext_vector_type(2)));

__global__ __launch_bounds__(128, 4) void snn_step_kernel(
    const float* __restrict__ x,       // [B,1,15,15]
    const float* __restrict__ conv_w,  // [2,1,4,4]
    const float* __restrict__ conv_b,  // [2]
    const float* __restrict__ lin_w,   // [10,72]
    const float* __restrict__ lin_b,   // [10]
    float* __restrict__ out,           // spk_out[B,10] ++ mem_rec[T,B,10] ++ spk_rec[T,B,10]
    int T, int B)
{
    const int b   = blockIdx.x;
    const int tid = threadIdx.x;
    const int w   = tid & 63;   // lane within wave
    const int wv  = tid >> 6;   // 0 = conv wave, 1 = enc+lin+dec wave

    __shared__ float s_convw[32];
    __shared__ float s_convb[2];
    __shared__ float s_linw[720];
    __shared__ float s_linb[10];
    __shared__ float s_z[8][304];   // 8-deep swizzled 15x15 tiles (+pad)
    __shared__ float s_p[8][72];    // wave0 -> wave1 handoff, 8-deep
    __shared__ float s_part[64];    // wave1-internal reduce buffer

    // ---- cooperative weight staging (128 threads) ----
    if (tid < 32) s_convw[tid] = conv_w[tid];
    if (tid < 2)  s_convb[tid] = conv_b[tid];
    for (int j = tid; j < 720; j += 128) s_linw[j] = lin_w[j];
    if (tid < 10) s_linb[tid] = lin_b[tid];
    __syncthreads();

    // ===== wave0 state =====
    v2f  wreg2[16];
    v2f  cb2 = (v2f){0.0f, 0.0f};
    int  wbase = 0;
    bool convlane = false;

    // ===== wave1 state =====
    float ve[4], cur[4];            // encoder: lane owns pixels w,w+64,w+128,w+192
    int   zoff[4];
    float lwreg[18];
    float lbias = 0.0f;
    float v = 0.0f, i_syn = 0.0f, sc = 0.0f;
    float svv[4], svs[4];           // deferred store values per sub-step
    const int lo = w >> 2, lq = w & 3;
    const bool olane = (w < 10);
    const size_t BO = (size_t)B * 10;
    float* mp  = out + BO + (size_t)b * 10 + w;          // lanes 0..9 contiguous
    float* spp = mp + (size_t)T * BO;

    const int roff[5] = {0, 16, 35, 51, 70};

    if (wv == 0) {
        convlane = (w < 36);
        int py = w / 6, px = w - py * 6;
        int wb = 35 * py + 2 * px;
        wbase = wb < 229 ? wb : 229;   // clamp keeps dead lanes in-bounds
#pragma unroll
        for (int kk = 0; kk < 16; ++kk) wreg2[kk] = (v2f){s_convw[kk], s_convw[16 + kk]};
        cb2 = (v2f){s_convb[0], s_convb[1]};
    } else {
        // encoder init (branchless; p>=225 -> pad region of the 304-float tile)
#pragma unroll
        for (int k = 0; k < 4; ++k) {
            int p = w + 64 * k;
            bool act = (p < 225);
            ve[k]  = 0.0f;
            cur[k] = act ? __fmul_rn(x[(size_t)b * 225 + p], 10.0f) : 0.0f;
            int row = p / 15, col = p - row * 15;
            zoff[k] = row * 16 + col + 3 * (row >> 1);   // swizzle; rows>=15 -> pad
        }
#pragma unroll
        for (int j = 0; j < 18; ++j) {
            int idx = lo * 72 + lq * 18 + j;
            lwreg[j] = s_linw[idx < 720 ? idx : 719];    // clamp for lanes >= 40
        }
        lbias = olane ? s_linb[w] : 0.0f;

        // prologue: enc(0..3) -> s_z slots 0..3 (consumed by wave0 in iter 0)
#pragma unroll
        for (int k = 0; k < 4; ++k) {
#pragma unroll
            for (int kk = 0; kk < 4; ++kk) {
                float vn = __fadd_rn(ve[kk], __fmul_rn(0.1f, __fsub_rn(cur[kk], ve[kk])));
                bool  sp = (vn > 1.0f);
                ve[kk] = sp ? 0.0f : vn;
                s_z[k][zoff[kk]] = sp ? 1.0f : 0.0f;
            }
        }
    }
    __syncthreads();   // prologue z visible to wave0

    // wave1: linear+decoder compute for one step; stores deferred into svv/svs[k].
    // s_part write -> b128 read round-trip (round-6 scheme; shfl was slower, r9).
    auto lin_comp = [&](const float* pbuf, int k) {
        const float* pp = &pbuf[lq * 18];
        float pv[18];
#pragma unroll
        for (int j = 0; j < 18; ++j) pv[j] = pp[j];
        float partial = 0.0f;
#pragma unroll
        for (int j = 0; j < 18; ++j)
            partial = fmaf(lwreg[j], pv[j], partial);
        s_part[w] = partial;

        float vd  = __fadd_rn(v, __fmul_rn(0.1f, __fsub_rn(i_syn, v)));
        float id  = __fsub_rn(i_syn, __fmul_rn(0.2f, i_syn));
        float spk = (vd > 1.0f) ? 1.0f : 0.0f;
        v = (vd > 1.0f) ? 0.0f : vd;
        sc += spk;
        svv[k] = v;
        svs[k] = spk;

        float4 pr = *(const float4*)&s_part[4 * (w < 10 ? w : 0)];
        float lin = __fadd_rn(__fadd_rn(__fadd_rn(__fadd_rn(pr.x, pr.y), pr.z), pr.w), lbias);
        i_syn = __fadd_rn(id, lin);
    };

    auto issue_stores = [&]() {
        if (olane) {
#pragma unroll
            for (int k = 0; k < 4; ++k) {
                mp[(size_t)k * BO]  = svv[k];
                spp[(size_t)k * BO] = svs[k];
            }
        }
        mp  += 4 * BO;
        spp += 4 * BO;
    };

    const int TI = T >> 2;   // T % 4 == 0

    for (int i = 0; i < TI; ++i) {
        const int rb = (i & 1) << 2;        // wave0 read slots rb..rb+3
        const int wb2 = rb ^ 4;             // wave1 write slots wb2..wb2+3
        if (wv == 0) {
#pragma unroll
            for (int k = 0; k < 4; ++k) {
                // conv window reads for step s=4i+k from s_z[rb|k]
                float zr[25];
                const float* zc = &s_z[rb | k][wbase];
#pragma unroll
                for (int r = 0; r < 5; ++r)
#pragma unroll
                    for (int cc = 0; cc < 5; ++cc)
                        zr[r * 5 + cc] = zc[roff[r] + cc];

                // conv 4x4 (channels packed) + maxpool 2x2 -> s_p[rb|k]
                if (convlane) {
                    v2f m2 = (v2f){-INFINITY, -INFINITY};
#pragma unroll
                    for (int dy = 0; dy < 2; ++dy)
#pragma unroll
                        for (int dx = 0; dx < 2; ++dx) {
                            v2f acc = (v2f){0.0f, 0.0f};
#pragma unroll
                            for (int ky = 0; ky < 4; ++ky)
#pragma unroll
                                for (int kx = 0; kx < 4; ++kx) {
                                    float z = zr[(dy + ky) * 5 + (dx + kx)];
                                    acc = __builtin_elementwise_fma(wreg2[ky * 4 + kx],
                                                                    (v2f){z, z}, acc);
                                }
                            v2f val = acc + cb2;
                            m2 = __builtin_elementwise_max(m2, val);
                        }
                    float* pbuf = s_p[rb | k];
                    pbuf[w]      = m2.x;
                    pbuf[36 + w] = m2.y;
                }
            }
        } else {
            if (i >= 2) issue_stores();     // steps 4(i-2)..4(i-2)+3
#pragma unroll
            for (int k = 0; k < 4; ++k) {
                if (i >= 1)
                    lin_comp(s_p[(rb ^ 4) | k], k);   // steps 4(i-1)..4(i-1)+3
                // encoder for step 4i+4+k -> s_z[wb2|k] (consumed next iter);
                // independent of lin_comp -> fills its s_part round-trip stall
#pragma unroll
                for (int kk = 0; kk < 4; ++kk) {
                    float vn = __fadd_rn(ve[kk], __fmul_rn(0.1f, __fsub_rn(cur[kk], ve[kk])));
                    bool  sp = (vn > 1.0f);
                    ve[kk] = sp ? 0.0f : vn;
                    s_z[wb2 | k][zoff[kk]] = sp ? 1.0f : 0.0f;
                }
            }
        }
        __syncthreads();
    }

    // ---- epilogue (wave1): pending stores T-8..T-5, compute+store T-4..T-1 ----
    if (wv == 1) {
        issue_stores();                     // steps T-8..T-5
        const int rb = ((TI - 1) & 1) << 2;
#pragma unroll
        for (int k = 0; k < 4; ++k)
            lin_comp(s_p[rb | k], k);       // steps T-4..T-1
        issue_stores();
        if (olane) out[(size_t)b * 10 + w] = sc;
    }
}

extern "C" void kernel_launch(void* const* d_in, const int* in_sizes, int n_in,
                              void* d_out, int out_size, void* d_ws, size_t ws_size,
                              hipStream_t stream) {
    const float* x      = (const float*)d_in[0];
    const float* conv_w = (const float*)d_in[1];
    const float* conv_b = (const float*)d_in[2];
    const float* lin_w  = (const float*)d_in[3];
    const float* lin_b  = (const float*)d_in[4];
    float* out = (float*)d_out;

    const int B = in_sizes[0] / 225;             // x is [B,1,15,15]
    const int T = (out_size / (B * 10) - 1) / 2; // out = B*10 * (1 + 2T); T=300 (div by 4)

    snn_step_kernel<<<B, 128, 0, stream>>>(x, conv_w, conv_b, lin_w, lin_b, out, T, B);
}